// Round 6
// baseline (264.729 us; speedup 1.0000x reference)
//
#include <hip/hip_runtime.h>
#include <hip/hip_bf16.h>
#include <math.h>

#define BB 8
#define DD 4096
#define NHQ 32
#define NKV 8
#define HD 128
#define KVL 4096
#define NSPLIT 32
#define CHUNK (KVL / NSPLIT)       // 128
#define SCALE 0.08838834764831845f // 1/sqrt(128)

// workspace layout (float offsets)
#define OFF_QROPE 0                           // 32768 floats
#define OFF_KROPE (OFF_QROPE + BB*NHQ*HD)     // 32768
#define OFF_VRAW  (OFF_KROPE + BB*NKV*HD)     // 40960
#define OFF_PART  (OFF_VRAW  + BB*NKV*HD)     // 49152
#define PART_STRIDE 132
#define OFF_CTX   (OFF_PART + BB*NHQ*NSPLIT*PART_STRIDE)

typedef float f32x4 __attribute__((ext_vector_type(4)));

__device__ __forceinline__ float4 ntload4(const float4* p) {
    f32x4 v = __builtin_nontemporal_load((const f32x4*)p);
    return make_float4(v.x, v.y, v.z, v.w);
}

// ---------------- K1: fused QKV projection + RoPE
__global__ __launch_bounds__(256) void k_qkv(
    const float* __restrict__ hs,
    const float* __restrict__ Wq, const float* __restrict__ bq,
    const float* __restrict__ Wk, const float* __restrict__ bk,
    const float* __restrict__ Wv, const float* __restrict__ bv,
    const int* __restrict__ posp,
    float* __restrict__ ws)
{
    const int wid  = threadIdx.x >> 6;
    const int lane = threadIdx.x & 63;
    const int w    = blockIdx.x * 4 + wid;   // 0..3071 wave-tasks

    const float* W; const float* bias; float* dst; int dstride; int r1; int i; bool rope;
    if (w < 2048) {                 // q rows: 32 heads x 64 pairs
        const int h = w >> 6; i = w & 63; r1 = h*HD + i;
        W = Wq; bias = bq; dst = ws + OFF_QROPE; dstride = NHQ*HD; rope = true;
    } else if (w < 2560) {          // k rows: 8 heads x 64 pairs
        const int w2 = w - 2048; const int h = w2 >> 6; i = w2 & 63; r1 = h*HD + i;
        W = Wk; bias = bk; dst = ws + OFF_KROPE; dstride = NKV*HD; rope = true;
    } else {                        // v rows: 8 heads x 64 pairs (no rope)
        const int w3 = w - 2560; const int h = w3 >> 6; i = w3 & 63; r1 = h*HD + i;
        W = Wv; bias = bv; dst = ws + OFF_VRAW; dstride = NKV*HD; rope = false;
    }
    const int r2 = r1 + 64;

    const double pos = (double)posp[0];
    const double ang = pos * pow(10000.0, -(double)i / 64.0);
    const float c = (float)cos(ang), s = (float)sin(ang);

    const float4* WrA = (const float4*)(W + (size_t)r1 * DD);
    const float4* WrB = (const float4*)(W + (size_t)r2 * DD);
    const float4* H   = (const float4*)hs;

    float accA[BB], accB[BB];
    #pragma unroll
    for (int b = 0; b < BB; ++b) { accA[b] = 0.f; accB[b] = 0.f; }

    for (int it = 0; it < DD/256; ++it) {      // 16 iterations
        const int idx = it*64 + lane;
        const float4 wa = ntload4(&WrA[idx]);
        const float4 wb = ntload4(&WrB[idx]);
        #pragma unroll
        for (int b = 0; b < BB; ++b) {
            const float4 h4 = H[b*(DD/4) + idx];
            accA[b] = fmaf(wa.x, h4.x, fmaf(wa.y, h4.y, fmaf(wa.z, h4.z, fmaf(wa.w, h4.w, accA[b]))));
            accB[b] = fmaf(wb.x, h4.x, fmaf(wb.y, h4.y, fmaf(wb.z, h4.z, fmaf(wb.w, h4.w, accB[b]))));
        }
    }
    #pragma unroll
    for (int b = 0; b < BB; ++b) {
        float va = accA[b], vb = accB[b];
        #pragma unroll
        for (int off = 32; off; off >>= 1) {
            va += __shfl_xor(va, off, 64);
            vb += __shfl_xor(vb, off, 64);
        }
        accA[b] = va; accB[b] = vb;
    }
    if (lane == 0) {
        const float b1 = bias[r1], b2 = bias[r2];
        #pragma unroll
        for (int b = 0; b < BB; ++b) {
            const float a1 = accA[b] + b1;
            const float a2 = accB[b] + b2;
            float o1, o2;
            if (rope) { o1 = fmaf(a1, c, -a2*s); o2 = fmaf(a2, c, a1*s); }
            else      { o1 = a1;                 o2 = a2; }
            dst[(size_t)b*dstride + r1] = o1;
            dst[(size_t)b*dstride + r2] = o2;
        }
    }
}

// ---------------- K2: branchless single-pass flash-decode, 16 rows/iteration
// one wave per (pair, split); per iteration: 8x1KB K loads + 8x1KB V loads
// (rows 16it..16it+15), 8 independent score-reduce chains, ONE shared rescale.
__global__ __launch_bounds__(256) void k_attn(
    const float* __restrict__ Kc, const float* __restrict__ Vc,
    float* __restrict__ ws)
{
    const int wid  = threadIdx.x >> 6;
    const int lane = threadIdx.x & 63;
    const int sub  = lane >> 5, l32 = lane & 31;
    const int task  = blockIdx.x * 4 + wid;     // 0..8191
    const int pair  = task >> 5;                // b*32 + h
    const int split = task & (NSPLIT - 1);
    const int b = pair >> 5, h = pair & 31;

    const float4 q4 = ((const float4*)(ws + OFF_QROPE + (size_t)pair * HD))[l32];
    const size_t base = ((size_t)pair * KVL + (size_t)split * CHUNK) * HD;
    const float4* Kp = (const float4*)(Kc + base);
    const float4* Vp = (const float4*)(Vc + base);

    float m = -1e30f, l = 0.f;
    float4 acc = {0.f, 0.f, 0.f, 0.f};

    for (int it = 0; it < CHUNK/16; ++it) {     // 8 iterations, 16 rows each
        const int r0 = it*16 + sub;
        float4 kr[8], vr[8];
        #pragma unroll
        for (int j = 0; j < 8; ++j) kr[j] = ntload4(&Kp[(r0 + 2*j)*32 + l32]);
        #pragma unroll
        for (int j = 0; j < 8; ++j) vr[j] = ntload4(&Vp[(r0 + 2*j)*32 + l32]);

        float sc[8];
        #pragma unroll
        for (int j = 0; j < 8; ++j)
            sc[j] = fmaf(q4.x, kr[j].x, fmaf(q4.y, kr[j].y, fmaf(q4.z, kr[j].z, q4.w*kr[j].w)));
        #pragma unroll
        for (int off = 16; off; off >>= 1) {
            #pragma unroll
            for (int j = 0; j < 8; ++j) sc[j] += __shfl_xor(sc[j], off, 64);
        }
        #pragma unroll
        for (int j = 0; j < 8; ++j) sc[j] *= SCALE;

        const float mx0 = fmaxf(fmaxf(sc[0], sc[1]), fmaxf(sc[2], sc[3]));
        const float mx1 = fmaxf(fmaxf(sc[4], sc[5]), fmaxf(sc[6], sc[7]));
        const float newm = fmaxf(fmaxf(mx0, mx1), m);
        const float r_ = __expf(m - newm);            // == 1.0 when m unchanged
        float e[8];
        #pragma unroll
        for (int j = 0; j < 8; ++j) e[j] = __expf(sc[j] - newm);
        m = newm;
        l = fmaf(l, r_, ((e[0]+e[1]) + (e[2]+e[3])) + ((e[4]+e[5]) + (e[6]+e[7])));
        acc.x = fmaf(acc.x, r_, (fmaf(e[0], vr[0].x, e[1]*vr[1].x) + fmaf(e[2], vr[2].x, e[3]*vr[3].x))
                              + (fmaf(e[4], vr[4].x, e[5]*vr[5].x) + fmaf(e[6], vr[6].x, e[7]*vr[7].x)));
        acc.y = fmaf(acc.y, r_, (fmaf(e[0], vr[0].y, e[1]*vr[1].y) + fmaf(e[2], vr[2].y, e[3]*vr[3].y))
                              + (fmaf(e[4], vr[4].y, e[5]*vr[5].y) + fmaf(e[6], vr[6].y, e[7]*vr[7].y)));
        acc.z = fmaf(acc.z, r_, (fmaf(e[0], vr[0].z, e[1]*vr[1].z) + fmaf(e[2], vr[2].z, e[3]*vr[3].z))
                              + (fmaf(e[4], vr[4].z, e[5]*vr[5].z) + fmaf(e[6], vr[6].z, e[7]*vr[7].z)));
        acc.w = fmaf(acc.w, r_, (fmaf(e[0], vr[0].w, e[1]*vr[1].w) + fmaf(e[2], vr[2].w, e[3]*vr[3].w))
                              + (fmaf(e[4], vr[4].w, e[5]*vr[5].w) + fmaf(e[6], vr[6].w, e[7]*vr[7].w)));
    }

    // append the new token (GQA: head h uses kv-head h/4) on the last split
    if (split == NSPLIT - 1 && sub == 0) {
        const float4 k4 = ((const float4*)(ws + OFF_KROPE + (size_t)(b*NKV + (h>>2)) * HD))[l32];
        const float4 v4 = ((const float4*)(ws + OFF_VRAW  + (size_t)(b*NKV + (h>>2)) * HD))[l32];
        float sv = fmaf(q4.x, k4.x, fmaf(q4.y, k4.y, fmaf(q4.z, k4.z, q4.w*k4.w)));
        #pragma unroll
        for (int off = 16; off; off >>= 1) sv += __shfl_xor(sv, off, 64);
        sv *= SCALE;
        const float newm = fmaxf(m, sv);
        const float r_ = __expf(m - newm);
        const float e  = __expf(sv - newm);
        m = newm;
        l = fmaf(l, r_, e);
        acc.x = fmaf(acc.x, r_, e*v4.x);
        acc.y = fmaf(acc.y, r_, e*v4.y);
        acc.z = fmaf(acc.z, r_, e*v4.z);
        acc.w = fmaf(acc.w, r_, e*v4.w);
    }

    // merge the two half-wave online states
    const float M  = fmaxf(m, __shfl_xor(m, 32, 64));
    const float r_ = __expf(m - M);
    l *= r_; acc.x *= r_; acc.y *= r_; acc.z *= r_; acc.w *= r_;
    l     += __shfl_xor(l,     32, 64);
    acc.x += __shfl_xor(acc.x, 32, 64);
    acc.y += __shfl_xor(acc.y, 32, 64);
    acc.z += __shfl_xor(acc.z, 32, 64);
    acc.w += __shfl_xor(acc.w, 32, 64);

    if (sub == 0) {
        float* pp = ws + OFF_PART + ((size_t)pair * NSPLIT + split) * PART_STRIDE;
        ((float4*)pp)[l32] = acc;
        if (l32 == 0) { pp[HD] = M; pp[HD+1] = l; }
    }
}

// ---------------- K3: combine splits (block per (b,h))
__global__ __launch_bounds__(128) void k_combine(float* __restrict__ ws)
{
    const int pair = blockIdx.x;
    const int d = threadIdx.x;
    const float* pp = ws + OFF_PART + (size_t)pair * NSPLIT * PART_STRIDE;
    __shared__ float sm[NSPLIT], sl[NSPLIT];
    if (d < NSPLIT) { sm[d] = pp[d*PART_STRIDE + HD]; sl[d] = pp[d*PART_STRIDE + HD + 1]; }
    __syncthreads();
    float M = -1e30f;
    #pragma unroll
    for (int s = 0; s < NSPLIT; ++s) M = fmaxf(M, sm[s]);
    float L = 0.f, acc = 0.f;
    #pragma unroll 8
    for (int s = 0; s < NSPLIT; ++s) {
        const float w = expf(sm[s] - M);
        L += sl[s] * w;
        acc = fmaf(pp[s*PART_STRIDE + d], w, acc);
    }
    ws[OFF_CTX + (size_t)pair*HD + d] = acc / L;
}

// ---------------- K4: output projection (wave per row, 8-batch accum)
__global__ __launch_bounds__(256) void k_oproj(
    const float* __restrict__ Wo, const float* __restrict__ ws, float* __restrict__ out)
{
    const int wid  = threadIdx.x >> 6;
    const int lane = threadIdx.x & 63;
    const int row  = blockIdx.x * 4 + wid;   // 0..4095
    const float4* Wr = (const float4*)(Wo + (size_t)row * DD);
    const float4* C  = (const float4*)(ws + OFF_CTX);
    float acc[BB];
    #pragma unroll
    for (int b = 0; b < BB; ++b) acc[b] = 0.f;
    for (int it = 0; it < DD/256; ++it) {
        const int idx = it*64 + lane;
        const float4 w4 = ntload4(&Wr[idx]);
        #pragma unroll
        for (int b = 0; b < BB; ++b) {
            const float4 h4 = C[b*(DD/4) + idx];
            acc[b] = fmaf(w4.x, h4.x, fmaf(w4.y, h4.y, fmaf(w4.z, h4.z, fmaf(w4.w, h4.w, acc[b]))));
        }
    }
    #pragma unroll
    for (int b = 0; b < BB; ++b) {
        float v = acc[b];
        #pragma unroll
        for (int off = 32; off; off >>= 1) v += __shfl_xor(v, off, 64);
        if (lane == 0) out[(size_t)b*DD + row] = v;
    }
}

extern "C" void kernel_launch(void* const* d_in, const int* in_sizes, int n_in,
                              void* d_out, int out_size, void* d_ws, size_t ws_size,
                              hipStream_t stream)
{
    const float* hs  = (const float*)d_in[0];
    const float* pk  = (const float*)d_in[1];
    const float* pv  = (const float*)d_in[2];
    const float* Wq  = (const float*)d_in[3];
    const float* bq  = (const float*)d_in[4];
    const float* Wk  = (const float*)d_in[5];
    const float* bk  = (const float*)d_in[6];
    const float* Wv  = (const float*)d_in[7];
    const float* bv  = (const float*)d_in[8];
    const float* Wo  = (const float*)d_in[9];
    const int*   pos = (const int*)d_in[10];
    float* out = (float*)d_out;
    float* ws  = (float*)d_ws;

    k_qkv    <<<3072/4,          256, 0, stream>>>(hs, Wq, bq, Wk, bk, Wv, bv, pos, ws);
    k_attn   <<<BB*NHQ*NSPLIT/4, 256, 0, stream>>>(pk, pv, ws);
    k_combine<<<BB*NHQ,          128, 0, stream>>>(ws);
    k_oproj  <<<4096/4,          256, 0, stream>>>(Wo, ws, out);
}

// Round 7
// 252.824 us; speedup vs baseline: 1.0471x; 1.0471x over previous
//
#include <hip/hip_runtime.h>
#include <hip/hip_bf16.h>
#include <math.h>

#define BB 8
#define DD 4096
#define NHQ 32
#define NKV 8
#define HD 128
#define KVL 4096
#define NSPLIT 32
#define CHUNK (KVL / NSPLIT)       // 128
#define SCALE 0.08838834764831845f // 1/sqrt(128)

// workspace layout (float offsets)
#define OFF_QROPE 0                           // 32768 floats
#define OFF_KROPE (OFF_QROPE + BB*NHQ*HD)     // 32768
#define OFF_VRAW  (OFF_KROPE + BB*NKV*HD)     // 40960
#define OFF_PART  (OFF_VRAW  + BB*NKV*HD)     // 49152
#define PART_STRIDE 132
#define OFF_CTX   (OFF_PART + BB*NHQ*NSPLIT*PART_STRIDE)

typedef float f32x4 __attribute__((ext_vector_type(4)));

__device__ __forceinline__ float4 ntload4(const float4* p) {
    f32x4 v = __builtin_nontemporal_load((const f32x4*)p);
    return make_float4(v.x, v.y, v.z, v.w);
}

__device__ __forceinline__ float dot4(const float4 a, const float4 b) {
    return fmaf(a.x, b.x, fmaf(a.y, b.y, fmaf(a.z, b.z, a.w*b.w)));
}

// ---------------- K1: fused QKV projection + RoPE
__global__ __launch_bounds__(256) void k_qkv(
    const float* __restrict__ hs,
    const float* __restrict__ Wq, const float* __restrict__ bq,
    const float* __restrict__ Wk, const float* __restrict__ bk,
    const float* __restrict__ Wv, const float* __restrict__ bv,
    const int* __restrict__ posp,
    float* __restrict__ ws)
{
    const int wid  = threadIdx.x >> 6;
    const int lane = threadIdx.x & 63;
    const int w    = blockIdx.x * 4 + wid;   // 0..3071 wave-tasks

    const float* W; const float* bias; float* dst; int dstride; int r1; int i; bool rope;
    if (w < 2048) {                 // q rows: 32 heads x 64 pairs
        const int h = w >> 6; i = w & 63; r1 = h*HD + i;
        W = Wq; bias = bq; dst = ws + OFF_QROPE; dstride = NHQ*HD; rope = true;
    } else if (w < 2560) {          // k rows: 8 heads x 64 pairs
        const int w2 = w - 2048; const int h = w2 >> 6; i = w2 & 63; r1 = h*HD + i;
        W = Wk; bias = bk; dst = ws + OFF_KROPE; dstride = NKV*HD; rope = true;
    } else {                        // v rows: 8 heads x 64 pairs (no rope)
        const int w3 = w - 2560; const int h = w3 >> 6; i = w3 & 63; r1 = h*HD + i;
        W = Wv; bias = bv; dst = ws + OFF_VRAW; dstride = NKV*HD; rope = false;
    }
    const int r2 = r1 + 64;

    const double pos = (double)posp[0];
    const double ang = pos * pow(10000.0, -(double)i / 64.0);
    const float c = (float)cos(ang), s = (float)sin(ang);

    const float4* WrA = (const float4*)(W + (size_t)r1 * DD);
    const float4* WrB = (const float4*)(W + (size_t)r2 * DD);
    const float4* H   = (const float4*)hs;

    float accA[BB], accB[BB];
    #pragma unroll
    for (int b = 0; b < BB; ++b) { accA[b] = 0.f; accB[b] = 0.f; }

    for (int it = 0; it < DD/256; ++it) {      // 16 iterations
        const int idx = it*64 + lane;
        const float4 wa = ntload4(&WrA[idx]);
        const float4 wb = ntload4(&WrB[idx]);
        #pragma unroll
        for (int b = 0; b < BB; ++b) {
            const float4 h4 = H[b*(DD/4) + idx];
            accA[b] = fmaf(wa.x, h4.x, fmaf(wa.y, h4.y, fmaf(wa.z, h4.z, fmaf(wa.w, h4.w, accA[b]))));
            accB[b] = fmaf(wb.x, h4.x, fmaf(wb.y, h4.y, fmaf(wb.z, h4.z, fmaf(wb.w, h4.w, accB[b]))));
        }
    }
    #pragma unroll
    for (int b = 0; b < BB; ++b) {
        float va = accA[b], vb = accB[b];
        #pragma unroll
        for (int off = 32; off; off >>= 1) {
            va += __shfl_xor(va, off, 64);
            vb += __shfl_xor(vb, off, 64);
        }
        accA[b] = va; accB[b] = vb;
    }
    if (lane == 0) {
        const float b1 = bias[r1], b2 = bias[r2];
        #pragma unroll
        for (int b = 0; b < BB; ++b) {
            const float a1 = accA[b] + b1;
            const float a2 = accB[b] + b2;
            float o1, o2;
            if (rope) { o1 = fmaf(a1, c, -a2*s); o2 = fmaf(a2, c, a1*s); }
            else      { o1 = a1;                 o2 = a2; }
            dst[(size_t)b*dstride + r1] = o1;
            dst[(size_t)b*dstride + r2] = o2;
        }
    }
}

// load group `it` (8 rows) into named registers
#define LOADG(k0_,k1_,k2_,k3_,v0_,v1_,v2_,v3_, it_) {            \
    const int r0_ = (it_)*8 + sub;                               \
    k0_ = ntload4(&Kp[(r0_+0)*32 + l32]);                        \
    k1_ = ntload4(&Kp[(r0_+2)*32 + l32]);                        \
    k2_ = ntload4(&Kp[(r0_+4)*32 + l32]);                        \
    k3_ = ntload4(&Kp[(r0_+6)*32 + l32]);                        \
    v0_ = ntload4(&Vp[(r0_+0)*32 + l32]);                        \
    v1_ = ntload4(&Vp[(r0_+2)*32 + l32]);                        \
    v2_ = ntload4(&Vp[(r0_+4)*32 + l32]);                        \
    v3_ = ntload4(&Vp[(r0_+6)*32 + l32]); }

// online-softmax update over one 8-row group held in named registers
#define COMPUTEG(k0_,k1_,k2_,k3_,v0_,v1_,v2_,v3_) {              \
    float s0 = dot4(q4, k0_), s1 = dot4(q4, k1_);                \
    float s2 = dot4(q4, k2_), s3 = dot4(q4, k3_);                \
    _Pragma("unroll")                                            \
    for (int off = 16; off; off >>= 1) {                         \
        s0 += __shfl_xor(s0, off, 64);                           \
        s1 += __shfl_xor(s1, off, 64);                           \
        s2 += __shfl_xor(s2, off, 64);                           \
        s3 += __shfl_xor(s3, off, 64);                           \
    }                                                            \
    s0 *= SCALE; s1 *= SCALE; s2 *= SCALE; s3 *= SCALE;          \
    const float newm = fmaxf(fmaxf(fmaxf(s0, s1), fmaxf(s2, s3)), m); \
    const float r_ = __expf(m - newm);                           \
    const float e0 = __expf(s0 - newm);                          \
    const float e1 = __expf(s1 - newm);                          \
    const float e2 = __expf(s2 - newm);                          \
    const float e3 = __expf(s3 - newm);                          \
    m = newm;                                                    \
    l = fmaf(l, r_, (e0 + e1) + (e2 + e3));                      \
    acc.x = fmaf(acc.x, r_, fmaf(e0, v0_.x, e1*v1_.x) + fmaf(e2, v2_.x, e3*v3_.x)); \
    acc.y = fmaf(acc.y, r_, fmaf(e0, v0_.y, e1*v1_.y) + fmaf(e2, v2_.y, e3*v3_.y)); \
    acc.z = fmaf(acc.z, r_, fmaf(e0, v0_.z, e1*v1_.z) + fmaf(e2, v2_.z, e3*v3_.z)); \
    acc.w = fmaf(acc.w, r_, fmaf(e0, v0_.w, e1*v1_.w) + fmaf(e2, v2_.w, e3*v3_.w)); }

// ---------------- K2: flash-decode, 8 rows/group, 2-deep register pipeline
// one wave per (pair, split); group i+1's 8x1KB loads issue BEFORE group i's
// compute, so HBM latency hides under the shuffle/exp phase. A/B named regs.
__global__ __launch_bounds__(256) void k_attn(
    const float* __restrict__ Kc, const float* __restrict__ Vc,
    float* __restrict__ ws)
{
    const int wid  = threadIdx.x >> 6;
    const int lane = threadIdx.x & 63;
    const int sub  = lane >> 5, l32 = lane & 31;
    const int task  = blockIdx.x * 4 + wid;     // 0..8191
    const int pair  = task >> 5;                // b*32 + h
    const int split = task & (NSPLIT - 1);
    const int b = pair >> 5, h = pair & 31;

    const float4 q4 = ((const float4*)(ws + OFF_QROPE + (size_t)pair * HD))[l32];
    const size_t base = ((size_t)pair * KVL + (size_t)split * CHUNK) * HD;
    const float4* Kp = (const float4*)(Kc + base);
    const float4* Vp = (const float4*)(Vc + base);

    float m = -1e30f, l = 0.f;
    float4 acc = {0.f, 0.f, 0.f, 0.f};

    float4 kA0, kA1, kA2, kA3, vA0, vA1, vA2, vA3;
    float4 kB0, kB1, kB2, kB3, vB0, vB1, vB2, vB3;

    LOADG(kA0,kA1,kA2,kA3, vA0,vA1,vA2,vA3, 0);
    for (int it2 = 0; it2 < CHUNK/16; ++it2) {   // 8 double-iterations
        LOADG(kB0,kB1,kB2,kB3, vB0,vB1,vB2,vB3, 2*it2 + 1);
        COMPUTEG(kA0,kA1,kA2,kA3, vA0,vA1,vA2,vA3);
        if (it2 < CHUNK/16 - 1)
            LOADG(kA0,kA1,kA2,kA3, vA0,vA1,vA2,vA3, 2*it2 + 2);
        COMPUTEG(kB0,kB1,kB2,kB3, vB0,vB1,vB2,vB3);
    }

    // append the new token (GQA: head h uses kv-head h/4) on the last split
    if (split == NSPLIT - 1 && sub == 0) {
        const float4 k4 = ((const float4*)(ws + OFF_KROPE + (size_t)(b*NKV + (h>>2)) * HD))[l32];
        const float4 v4 = ((const float4*)(ws + OFF_VRAW  + (size_t)(b*NKV + (h>>2)) * HD))[l32];
        float sv = dot4(q4, k4);
        #pragma unroll
        for (int off = 16; off; off >>= 1) sv += __shfl_xor(sv, off, 64);
        sv *= SCALE;
        const float newm = fmaxf(m, sv);
        const float r_ = __expf(m - newm);
        const float e  = __expf(sv - newm);
        m = newm;
        l = fmaf(l, r_, e);
        acc.x = fmaf(acc.x, r_, e*v4.x);
        acc.y = fmaf(acc.y, r_, e*v4.y);
        acc.z = fmaf(acc.z, r_, e*v4.z);
        acc.w = fmaf(acc.w, r_, e*v4.w);
    }

    // merge the two half-wave online states
    const float M  = fmaxf(m, __shfl_xor(m, 32, 64));
    const float r2_ = __expf(m - M);
    l *= r2_; acc.x *= r2_; acc.y *= r2_; acc.z *= r2_; acc.w *= r2_;
    l     += __shfl_xor(l,     32, 64);
    acc.x += __shfl_xor(acc.x, 32, 64);
    acc.y += __shfl_xor(acc.y, 32, 64);
    acc.z += __shfl_xor(acc.z, 32, 64);
    acc.w += __shfl_xor(acc.w, 32, 64);

    if (sub == 0) {
        float* pp = ws + OFF_PART + ((size_t)pair * NSPLIT + split) * PART_STRIDE;
        ((float4*)pp)[l32] = acc;
        if (l32 == 0) { pp[HD] = M; pp[HD+1] = l; }
    }
}

// ---------------- K3: combine splits (block per (b,h))
__global__ __launch_bounds__(128) void k_combine(float* __restrict__ ws)
{
    const int pair = blockIdx.x;
    const int d = threadIdx.x;
    const float* pp = ws + OFF_PART + (size_t)pair * NSPLIT * PART_STRIDE;
    __shared__ float sm[NSPLIT], sl[NSPLIT];
    if (d < NSPLIT) { sm[d] = pp[d*PART_STRIDE + HD]; sl[d] = pp[d*PART_STRIDE + HD + 1]; }
    __syncthreads();
    float M = -1e30f;
    #pragma unroll
    for (int s = 0; s < NSPLIT; ++s) M = fmaxf(M, sm[s]);
    float L = 0.f, acc = 0.f;
    #pragma unroll 8
    for (int s = 0; s < NSPLIT; ++s) {
        const float w = expf(sm[s] - M);
        L += sl[s] * w;
        acc = fmaf(pp[s*PART_STRIDE + d], w, acc);
    }
    ws[OFF_CTX + (size_t)pair*HD + d] = acc / L;
}

// ---------------- K4: output projection (wave per row, 8-batch accum)
__global__ __launch_bounds__(256) void k_oproj(
    const float* __restrict__ Wo, const float* __restrict__ ws, float* __restrict__ out)
{
    const int wid  = threadIdx.x >> 6;
    const int lane = threadIdx.x & 63;
    const int row  = blockIdx.x * 4 + wid;   // 0..4095
    const float4* Wr = (const float4*)(Wo + (size_t)row * DD);
    const float4* C  = (const float4*)(ws + OFF_CTX);
    float acc[BB];
    #pragma unroll
    for (int b = 0; b < BB; ++b) acc[b] = 0.f;
    for (int it = 0; it < DD/256; ++it) {
        const int idx = it*64 + lane;
        const float4 w4 = ntload4(&Wr[idx]);
        #pragma unroll
        for (int b = 0; b < BB; ++b) {
            const float4 h4 = C[b*(DD/4) + idx];
            acc[b] = fmaf(w4.x, h4.x, fmaf(w4.y, h4.y, fmaf(w4.z, h4.z, fmaf(w4.w, h4.w, acc[b]))));
        }
    }
    #pragma unroll
    for (int b = 0; b < BB; ++b) {
        float v = acc[b];
        #pragma unroll
        for (int off = 32; off; off >>= 1) v += __shfl_xor(v, off, 64);
        if (lane == 0) out[(size_t)b*DD + row] = v;
    }
}

extern "C" void kernel_launch(void* const* d_in, const int* in_sizes, int n_in,
                              void* d_out, int out_size, void* d_ws, size_t ws_size,
                              hipStream_t stream)
{
    const float* hs  = (const float*)d_in[0];
    const float* pk  = (const float*)d_in[1];
    const float* pv  = (const float*)d_in[2];
    const float* Wq  = (const float*)d_in[3];
    const float* bq  = (const float*)d_in[4];
    const float* Wk  = (const float*)d_in[5];
    const float* bk  = (const float*)d_in[6];
    const float* Wv  = (const float*)d_in[7];
    const float* bv  = (const float*)d_in[8];
    const float* Wo  = (const float*)d_in[9];
    const int*   pos = (const int*)d_in[10];
    float* out = (float*)d_out;
    float* ws  = (float*)d_ws;

    k_qkv    <<<3072/4,          256, 0, stream>>>(hs, Wq, bq, Wk, bk, Wv, bv, pos, ws);
    k_attn   <<<BB*NHQ*NSPLIT/4, 256, 0, stream>>>(pk, pv, ws);
    k_combine<<<BB*NHQ,          128, 0, stream>>>(ws);
    k_oproj  <<<4096/4,          256, 0, stream>>>(Wo, ws, out);
}

// Round 8
// 251.001 us; speedup vs baseline: 1.0547x; 1.0073x over previous
//
#include <hip/hip_runtime.h>
#include <hip/hip_bf16.h>
#include <math.h>

#define BB 8
#define DD 4096
#define NHQ 32
#define NKV 8
#define HD 128
#define KVL 4096
#define NSPLIT 32
#define CHUNK (KVL / NSPLIT)       // 128
#define SCALE 0.08838834764831845f // 1/sqrt(128)

// workspace layout (float offsets)
#define OFF_QROPE 0                           // 32768 floats
#define OFF_KROPE (OFF_QROPE + BB*NHQ*HD)     // 32768
#define OFF_VRAW  (OFF_KROPE + BB*NKV*HD)     // 40960
#define OFF_PART  (OFF_VRAW  + BB*NKV*HD)     // 49152
#define PART_STRIDE 132
#define OFF_CTX   (OFF_PART + BB*NHQ*NSPLIT*PART_STRIDE)

typedef float f32x4 __attribute__((ext_vector_type(4)));

__device__ __forceinline__ float4 ntload4(const float4* p) {
    f32x4 v = __builtin_nontemporal_load((const f32x4*)p);
    return make_float4(v.x, v.y, v.z, v.w);
}

__device__ __forceinline__ float dot4(const float4 a, const float4 b) {
    return fmaf(a.x, b.x, fmaf(a.y, b.y, fmaf(a.z, b.z, a.w*b.w)));
}

// ---------------- K1: fused QKV projection + RoPE
__global__ __launch_bounds__(256) void k_qkv(
    const float* __restrict__ hs,
    const float* __restrict__ Wq, const float* __restrict__ bq,
    const float* __restrict__ Wk, const float* __restrict__ bk,
    const float* __restrict__ Wv, const float* __restrict__ bv,
    const int* __restrict__ posp,
    float* __restrict__ ws)
{
    const int wid  = threadIdx.x >> 6;
    const int lane = threadIdx.x & 63;
    const int w    = blockIdx.x * 4 + wid;   // 0..3071 wave-tasks

    const float* W; const float* bias; float* dst; int dstride; int r1; int i; bool rope;
    if (w < 2048) {                 // q rows: 32 heads x 64 pairs
        const int h = w >> 6; i = w & 63; r1 = h*HD + i;
        W = Wq; bias = bq; dst = ws + OFF_QROPE; dstride = NHQ*HD; rope = true;
    } else if (w < 2560) {          // k rows: 8 heads x 64 pairs
        const int w2 = w - 2048; const int h = w2 >> 6; i = w2 & 63; r1 = h*HD + i;
        W = Wk; bias = bk; dst = ws + OFF_KROPE; dstride = NKV*HD; rope = true;
    } else {                        // v rows: 8 heads x 64 pairs (no rope)
        const int w3 = w - 2560; const int h = w3 >> 6; i = w3 & 63; r1 = h*HD + i;
        W = Wv; bias = bv; dst = ws + OFF_VRAW; dstride = NKV*HD; rope = false;
    }
    const int r2 = r1 + 64;

    const double pos = (double)posp[0];
    const double ang = pos * pow(10000.0, -(double)i / 64.0);
    const float c = (float)cos(ang), s = (float)sin(ang);

    const float4* WrA = (const float4*)(W + (size_t)r1 * DD);
    const float4* WrB = (const float4*)(W + (size_t)r2 * DD);
    const float4* H   = (const float4*)hs;

    float accA[BB], accB[BB];
    #pragma unroll
    for (int b = 0; b < BB; ++b) { accA[b] = 0.f; accB[b] = 0.f; }

    for (int it = 0; it < DD/256; ++it) {      // 16 iterations
        const int idx = it*64 + lane;
        const float4 wa = ntload4(&WrA[idx]);
        const float4 wb = ntload4(&WrB[idx]);
        #pragma unroll
        for (int b = 0; b < BB; ++b) {
            const float4 h4 = H[b*(DD/4) + idx];
            accA[b] = fmaf(wa.x, h4.x, fmaf(wa.y, h4.y, fmaf(wa.z, h4.z, fmaf(wa.w, h4.w, accA[b]))));
            accB[b] = fmaf(wb.x, h4.x, fmaf(wb.y, h4.y, fmaf(wb.z, h4.z, fmaf(wb.w, h4.w, accB[b]))));
        }
    }
    #pragma unroll
    for (int b = 0; b < BB; ++b) {
        float va = accA[b], vb = accB[b];
        #pragma unroll
        for (int off = 32; off; off >>= 1) {
            va += __shfl_xor(va, off, 64);
            vb += __shfl_xor(vb, off, 64);
        }
        accA[b] = va; accB[b] = vb;
    }
    if (lane == 0) {
        const float b1 = bias[r1], b2 = bias[r2];
        #pragma unroll
        for (int b = 0; b < BB; ++b) {
            const float a1 = accA[b] + b1;
            const float a2 = accB[b] + b2;
            float o1, o2;
            if (rope) { o1 = fmaf(a1, c, -a2*s); o2 = fmaf(a2, c, a1*s); }
            else      { o1 = a1;                 o2 = a2; }
            dst[(size_t)b*dstride + r1] = o1;
            dst[(size_t)b*dstride + r2] = o2;
        }
    }
}

// ---------------- K2: flash-decode, 16 rows/iter, K-then-V register time-share
// one wave per (pair, split). Per iteration: 8x1KB K burst -> dot4s free the K
// regs -> 8x1KB V burst reuses them; shuffle/exp phase overlaps V latency.
// __launch_bounds__(256,8) caps VGPR at 64 -> 8 waves/SIMD, all blocks resident.
__global__ __launch_bounds__(256, 8) void k_attn(
    const float* __restrict__ Kc, const float* __restrict__ Vc,
    float* __restrict__ ws)
{
    const int wid  = threadIdx.x >> 6;
    const int lane = threadIdx.x & 63;
    const int sub  = lane >> 5, l32 = lane & 31;
    const int task  = blockIdx.x * 4 + wid;     // 0..8191
    const int pair  = task >> 5;                // b*32 + h
    const int split = task & (NSPLIT - 1);
    const int b = pair >> 5, h = pair & 31;

    const float4 q4 = ((const float4*)(ws + OFF_QROPE + (size_t)pair * HD))[l32];
    const size_t base = ((size_t)pair * KVL + (size_t)split * CHUNK) * HD;
    const float4* Kp = (const float4*)(Kc + base);
    const float4* Vp = (const float4*)(Vc + base);

    float m = -1e30f, l = 0.f;
    float4 acc = {0.f, 0.f, 0.f, 0.f};

    for (int it = 0; it < CHUNK/16; ++it) {     // 8 iterations, 16 rows each
        const int r0 = it*16 + sub;
        // K burst: 8 x 1KB contiguous (rows 16it..16it+15)
        const float4 k0 = ntload4(&Kp[(r0+ 0)*32 + l32]);
        const float4 k1 = ntload4(&Kp[(r0+ 2)*32 + l32]);
        const float4 k2 = ntload4(&Kp[(r0+ 4)*32 + l32]);
        const float4 k3 = ntload4(&Kp[(r0+ 6)*32 + l32]);
        const float4 k4 = ntload4(&Kp[(r0+ 8)*32 + l32]);
        const float4 k5 = ntload4(&Kp[(r0+10)*32 + l32]);
        const float4 k6 = ntload4(&Kp[(r0+12)*32 + l32]);
        const float4 k7 = ntload4(&Kp[(r0+14)*32 + l32]);
        // dots kill the K registers
        float s0 = dot4(q4, k0), s1 = dot4(q4, k1);
        float s2 = dot4(q4, k2), s3 = dot4(q4, k3);
        float s4 = dot4(q4, k4), s5 = dot4(q4, k5);
        float s6 = dot4(q4, k6), s7 = dot4(q4, k7);
        // V burst reuses the freed registers; latency hides under the shuffles
        const float4 v0 = ntload4(&Vp[(r0+ 0)*32 + l32]);
        const float4 v1 = ntload4(&Vp[(r0+ 2)*32 + l32]);
        const float4 v2 = ntload4(&Vp[(r0+ 4)*32 + l32]);
        const float4 v3 = ntload4(&Vp[(r0+ 6)*32 + l32]);
        const float4 v4 = ntload4(&Vp[(r0+ 8)*32 + l32]);
        const float4 v5 = ntload4(&Vp[(r0+10)*32 + l32]);
        const float4 v6 = ntload4(&Vp[(r0+12)*32 + l32]);
        const float4 v7 = ntload4(&Vp[(r0+14)*32 + l32]);

        #pragma unroll
        for (int off = 16; off; off >>= 1) {
            s0 += __shfl_xor(s0, off, 64);
            s1 += __shfl_xor(s1, off, 64);
            s2 += __shfl_xor(s2, off, 64);
            s3 += __shfl_xor(s3, off, 64);
            s4 += __shfl_xor(s4, off, 64);
            s5 += __shfl_xor(s5, off, 64);
            s6 += __shfl_xor(s6, off, 64);
            s7 += __shfl_xor(s7, off, 64);
        }
        s0 *= SCALE; s1 *= SCALE; s2 *= SCALE; s3 *= SCALE;
        s4 *= SCALE; s5 *= SCALE; s6 *= SCALE; s7 *= SCALE;

        const float mx0 = fmaxf(fmaxf(s0, s1), fmaxf(s2, s3));
        const float mx1 = fmaxf(fmaxf(s4, s5), fmaxf(s6, s7));
        const float newm = fmaxf(fmaxf(mx0, mx1), m);
        const float r_ = __expf(m - newm);            // == 1.0 when m unchanged
        const float e0 = __expf(s0 - newm);
        const float e1 = __expf(s1 - newm);
        const float e2 = __expf(s2 - newm);
        const float e3 = __expf(s3 - newm);
        const float e4 = __expf(s4 - newm);
        const float e5 = __expf(s5 - newm);
        const float e6 = __expf(s6 - newm);
        const float e7 = __expf(s7 - newm);
        m = newm;
        l = fmaf(l, r_, ((e0+e1) + (e2+e3)) + ((e4+e5) + (e6+e7)));
        acc.x = fmaf(acc.x, r_, (fmaf(e0, v0.x, e1*v1.x) + fmaf(e2, v2.x, e3*v3.x))
                              + (fmaf(e4, v4.x, e5*v5.x) + fmaf(e6, v6.x, e7*v7.x)));
        acc.y = fmaf(acc.y, r_, (fmaf(e0, v0.y, e1*v1.y) + fmaf(e2, v2.y, e3*v3.y))
                              + (fmaf(e4, v4.y, e5*v5.y) + fmaf(e6, v6.y, e7*v7.y)));
        acc.z = fmaf(acc.z, r_, (fmaf(e0, v0.z, e1*v1.z) + fmaf(e2, v2.z, e3*v3.z))
                              + (fmaf(e4, v4.z, e5*v5.z) + fmaf(e6, v6.z, e7*v7.z)));
        acc.w = fmaf(acc.w, r_, (fmaf(e0, v0.w, e1*v1.w) + fmaf(e2, v2.w, e3*v3.w))
                              + (fmaf(e4, v4.w, e5*v5.w) + fmaf(e6, v6.w, e7*v7.w)));
    }

    // append the new token (GQA: head h uses kv-head h/4) on the last split
    if (split == NSPLIT - 1 && sub == 0) {
        const float4 kn = ((const float4*)(ws + OFF_KROPE + (size_t)(b*NKV + (h>>2)) * HD))[l32];
        const float4 vn = ((const float4*)(ws + OFF_VRAW  + (size_t)(b*NKV + (h>>2)) * HD))[l32];
        float sv = dot4(q4, kn);
        #pragma unroll
        for (int off = 16; off; off >>= 1) sv += __shfl_xor(sv, off, 64);
        sv *= SCALE;
        const float newm = fmaxf(m, sv);
        const float r_ = __expf(m - newm);
        const float e  = __expf(sv - newm);
        m = newm;
        l = fmaf(l, r_, e);
        acc.x = fmaf(acc.x, r_, e*vn.x);
        acc.y = fmaf(acc.y, r_, e*vn.y);
        acc.z = fmaf(acc.z, r_, e*vn.z);
        acc.w = fmaf(acc.w, r_, e*vn.w);
    }

    // merge the two half-wave online states
    const float M  = fmaxf(m, __shfl_xor(m, 32, 64));
    const float r2_ = __expf(m - M);
    l *= r2_; acc.x *= r2_; acc.y *= r2_; acc.z *= r2_; acc.w *= r2_;
    l     += __shfl_xor(l,     32, 64);
    acc.x += __shfl_xor(acc.x, 32, 64);
    acc.y += __shfl_xor(acc.y, 32, 64);
    acc.z += __shfl_xor(acc.z, 32, 64);
    acc.w += __shfl_xor(acc.w, 32, 64);

    if (sub == 0) {
        float* pp = ws + OFF_PART + ((size_t)pair * NSPLIT + split) * PART_STRIDE;
        ((float4*)pp)[l32] = acc;
        if (l32 == 0) { pp[HD] = M; pp[HD+1] = l; }
    }
}

// ---------------- K3: combine splits (block per (b,h))
__global__ __launch_bounds__(128) void k_combine(float* __restrict__ ws)
{
    const int pair = blockIdx.x;
    const int d = threadIdx.x;
    const float* pp = ws + OFF_PART + (size_t)pair * NSPLIT * PART_STRIDE;
    __shared__ float sm[NSPLIT], sl[NSPLIT];
    if (d < NSPLIT) { sm[d] = pp[d*PART_STRIDE + HD]; sl[d] = pp[d*PART_STRIDE + HD + 1]; }
    __syncthreads();
    float M = -1e30f;
    #pragma unroll
    for (int s = 0; s < NSPLIT; ++s) M = fmaxf(M, sm[s]);
    float L = 0.f, acc = 0.f;
    #pragma unroll 8
    for (int s = 0; s < NSPLIT; ++s) {
        const float w = expf(sm[s] - M);
        L += sl[s] * w;
        acc = fmaf(pp[s*PART_STRIDE + d], w, acc);
    }
    ws[OFF_CTX + (size_t)pair*HD + d] = acc / L;
}

// ---------------- K4: output projection (wave per row, 8-batch accum)
__global__ __launch_bounds__(256) void k_oproj(
    const float* __restrict__ Wo, const float* __restrict__ ws, float* __restrict__ out)
{
    const int wid  = threadIdx.x >> 6;
    const int lane = threadIdx.x & 63;
    const int row  = blockIdx.x * 4 + wid;   // 0..4095
    const float4* Wr = (const float4*)(Wo + (size_t)row * DD);
    const float4* C  = (const float4*)(ws + OFF_CTX);
    float acc[BB];
    #pragma unroll
    for (int b = 0; b < BB; ++b) acc[b] = 0.f;
    for (int it = 0; it < DD/256; ++it) {
        const int idx = it*64 + lane;
        const float4 w4 = ntload4(&Wr[idx]);
        #pragma unroll
        for (int b = 0; b < BB; ++b) {
            const float4 h4 = C[b*(DD/4) + idx];
            acc[b] = fmaf(w4.x, h4.x, fmaf(w4.y, h4.y, fmaf(w4.z, h4.z, fmaf(w4.w, h4.w, acc[b]))));
        }
    }
    #pragma unroll
    for (int b = 0; b < BB; ++b) {
        float v = acc[b];
        #pragma unroll
        for (int off = 32; off; off >>= 1) v += __shfl_xor(v, off, 64);
        if (lane == 0) out[(size_t)b*DD + row] = v;
    }
}

extern "C" void kernel_launch(void* const* d_in, const int* in_sizes, int n_in,
                              void* d_out, int out_size, void* d_ws, size_t ws_size,
                              hipStream_t stream)
{
    const float* hs  = (const float*)d_in[0];
    const float* pk  = (const float*)d_in[1];
    const float* pv  = (const float*)d_in[2];
    const float* Wq  = (const float*)d_in[3];
    const float* bq  = (const float*)d_in[4];
    const float* Wk  = (const float*)d_in[5];
    const float* bk  = (const float*)d_in[6];
    const float* Wv  = (const float*)d_in[7];
    const float* bv  = (const float*)d_in[8];
    const float* Wo  = (const float*)d_in[9];
    const int*   pos = (const int*)d_in[10];
    float* out = (float*)d_out;
    float* ws  = (float*)d_ws;

    k_qkv    <<<3072/4,          256, 0, stream>>>(hs, Wq, bq, Wk, bk, Wv, bv, pos, ws);
    k_attn   <<<BB*NHQ*NSPLIT/4, 256, 0, stream>>>(pk, pv, ws);
    k_combine<<<BB*NHQ,          128, 0, stream>>>(ws);
    k_oproj  <<<4096/4,          256, 0, stream>>>(Wo, ws, out);
}

// Round 9
// 246.030 us; speedup vs baseline: 1.0760x; 1.0202x over previous
//
#include <hip/hip_runtime.h>
#include <hip/hip_bf16.h>
#include <math.h>

#define BB 8
#define DD 4096
#define NHQ 32
#define NKV 8
#define HD 128
#define KVL 4096
#define NSPLIT 32
#define CHUNK (KVL / NSPLIT)       // 128
#define SCALE 0.08838834764831845f // 1/sqrt(128)

// workspace layout (float offsets)
#define OFF_QROPE 0                           // 32768 floats
#define OFF_KROPE (OFF_QROPE + BB*NHQ*HD)     // 32768
#define OFF_VRAW  (OFF_KROPE + BB*NKV*HD)     // 40960
#define OFF_PART  (OFF_VRAW  + BB*NKV*HD)     // 49152
#define PART_STRIDE 132
#define OFF_CTX   (OFF_PART + BB*NHQ*NSPLIT*PART_STRIDE)

typedef float f32x4 __attribute__((ext_vector_type(4)));

__device__ __forceinline__ float4 ntload4(const float4* p) {
    f32x4 v = __builtin_nontemporal_load((const f32x4*)p);
    return make_float4(v.x, v.y, v.z, v.w);
}

__device__ __forceinline__ float dot4(const float4 a, const float4 b) {
    return fmaf(a.x, b.x, fmaf(a.y, b.y, fmaf(a.z, b.z, a.w*b.w)));
}

// ---------------- K1: fused QKV projection + RoPE
__global__ __launch_bounds__(256) void k_qkv(
    const float* __restrict__ hs,
    const float* __restrict__ Wq, const float* __restrict__ bq,
    const float* __restrict__ Wk, const float* __restrict__ bk,
    const float* __restrict__ Wv, const float* __restrict__ bv,
    const int* __restrict__ posp,
    float* __restrict__ ws)
{
    const int wid  = threadIdx.x >> 6;
    const int lane = threadIdx.x & 63;
    const int w    = blockIdx.x * 4 + wid;   // 0..3071 wave-tasks

    const float* W; const float* bias; float* dst; int dstride; int r1; int i; bool rope;
    if (w < 2048) {                 // q rows: 32 heads x 64 pairs
        const int h = w >> 6; i = w & 63; r1 = h*HD + i;
        W = Wq; bias = bq; dst = ws + OFF_QROPE; dstride = NHQ*HD; rope = true;
    } else if (w < 2560) {          // k rows: 8 heads x 64 pairs
        const int w2 = w - 2048; const int h = w2 >> 6; i = w2 & 63; r1 = h*HD + i;
        W = Wk; bias = bk; dst = ws + OFF_KROPE; dstride = NKV*HD; rope = true;
    } else {                        // v rows: 8 heads x 64 pairs (no rope)
        const int w3 = w - 2560; const int h = w3 >> 6; i = w3 & 63; r1 = h*HD + i;
        W = Wv; bias = bv; dst = ws + OFF_VRAW; dstride = NKV*HD; rope = false;
    }
    const int r2 = r1 + 64;

    const double pos = (double)posp[0];
    const double ang = pos * pow(10000.0, -(double)i / 64.0);
    const float c = (float)cos(ang), s = (float)sin(ang);

    const float4* WrA = (const float4*)(W + (size_t)r1 * DD);
    const float4* WrB = (const float4*)(W + (size_t)r2 * DD);
    const float4* H   = (const float4*)hs;

    float accA[BB], accB[BB];
    #pragma unroll
    for (int b = 0; b < BB; ++b) { accA[b] = 0.f; accB[b] = 0.f; }

    for (int it = 0; it < DD/256; ++it) {      // 16 iterations
        const int idx = it*64 + lane;
        const float4 wa = ntload4(&WrA[idx]);
        const float4 wb = ntload4(&WrB[idx]);
        #pragma unroll
        for (int b = 0; b < BB; ++b) {
            const float4 h4 = H[b*(DD/4) + idx];
            accA[b] = fmaf(wa.x, h4.x, fmaf(wa.y, h4.y, fmaf(wa.z, h4.z, fmaf(wa.w, h4.w, accA[b]))));
            accB[b] = fmaf(wb.x, h4.x, fmaf(wb.y, h4.y, fmaf(wb.z, h4.z, fmaf(wb.w, h4.w, accB[b]))));
        }
    }
    #pragma unroll
    for (int b = 0; b < BB; ++b) {
        float va = accA[b], vb = accB[b];
        #pragma unroll
        for (int off = 32; off; off >>= 1) {
            va += __shfl_xor(va, off, 64);
            vb += __shfl_xor(vb, off, 64);
        }
        accA[b] = va; accB[b] = vb;
    }
    if (lane == 0) {
        const float b1 = bias[r1], b2 = bias[r2];
        #pragma unroll
        for (int b = 0; b < BB; ++b) {
            const float a1 = accA[b] + b1;
            const float a2 = accB[b] + b2;
            float o1, o2;
            if (rope) { o1 = fmaf(a1, c, -a2*s); o2 = fmaf(a2, c, a1*s); }
            else      { o1 = a1;                 o2 = a2; }
            dst[(size_t)b*dstride + r1] = o1;
            dst[(size_t)b*dstride + r2] = o2;
        }
    }
}

// ---------------- K2: two-phase flash-decode split
// one wave per (pair, split). Phase K: stream 64KB K contiguously, raw scores
// -> wave-private LDS slab (no rescale, running max in reg). Phase V: stream
// 64KB V contiguously, exp+fma only. No barriers; one stream per phase.
__global__ __launch_bounds__(256) void k_attn(
    const float* __restrict__ Kc, const float* __restrict__ Vc,
    float* __restrict__ ws)
{
    __shared__ float sc_lds[4][CHUNK];

    const int wid  = threadIdx.x >> 6;
    const int lane = threadIdx.x & 63;
    const int sub  = lane >> 5, l32 = lane & 31;
    const int task  = blockIdx.x * 4 + wid;     // 0..8191
    const int pair  = task >> 5;                // b*32 + h
    const int split = task & (NSPLIT - 1);
    const int b = pair >> 5, h = pair & 31;
    float* swv = sc_lds[wid];

    const float4 q4 = ((const float4*)(ws + OFF_QROPE + (size_t)pair * HD))[l32];
    const size_t base = ((size_t)pair * KVL + (size_t)split * CHUNK) * HD;
    const float4* Kp = (const float4*)(Kc + base);
    const float4* Vp = (const float4*)(Vc + base);

    // ---- phase K: scores for 128 rows, one long 64KB sequential stream
    float m0 = -1e30f;
    for (int it = 0; it < CHUNK/8; ++it) {      // 16 iters, 8 rows each
        const int r0 = it*8 + sub;
        const float4 k0 = ntload4(&Kp[(r0+0)*32 + l32]);
        const float4 k1 = ntload4(&Kp[(r0+2)*32 + l32]);
        const float4 k2 = ntload4(&Kp[(r0+4)*32 + l32]);
        const float4 k3 = ntload4(&Kp[(r0+6)*32 + l32]);
        float s0 = dot4(q4, k0), s1 = dot4(q4, k1);
        float s2 = dot4(q4, k2), s3 = dot4(q4, k3);
        #pragma unroll
        for (int off = 16; off; off >>= 1) {
            s0 += __shfl_xor(s0, off, 64);
            s1 += __shfl_xor(s1, off, 64);
            s2 += __shfl_xor(s2, off, 64);
            s3 += __shfl_xor(s3, off, 64);
        }
        s0 *= SCALE; s1 *= SCALE; s2 *= SCALE; s3 *= SCALE;
        m0 = fmaxf(m0, fmaxf(fmaxf(s0, s1), fmaxf(s2, s3)));
        if (l32 == 0) {   // one writer lane per sub-half (rows r0, r0+2, ...)
            swv[r0+0] = s0; swv[r0+2] = s1; swv[r0+4] = s2; swv[r0+6] = s3;
        }
    }
    float m = fmaxf(m0, __shfl_xor(m0, 32, 64));   // merge sub-half maxima

    // ---- phase V: weighted sum, one long 64KB sequential stream
    float l = 0.f;
    float4 acc = {0.f, 0.f, 0.f, 0.f};
    for (int it = 0; it < CHUNK/8; ++it) {      // 16 iters, 8 rows each
        const int r0 = it*8 + sub;
        const float4 v0 = ntload4(&Vp[(r0+0)*32 + l32]);
        const float4 v1 = ntload4(&Vp[(r0+2)*32 + l32]);
        const float4 v2 = ntload4(&Vp[(r0+4)*32 + l32]);
        const float4 v3 = ntload4(&Vp[(r0+6)*32 + l32]);
        const float e0 = __expf(swv[r0+0] - m);
        const float e1 = __expf(swv[r0+2] - m);
        const float e2 = __expf(swv[r0+4] - m);
        const float e3 = __expf(swv[r0+6] - m);
        l += (e0 + e1) + (e2 + e3);
        acc.x += fmaf(e0, v0.x, e1*v1.x) + fmaf(e2, v2.x, e3*v3.x);
        acc.y += fmaf(e0, v0.y, e1*v1.y) + fmaf(e2, v2.y, e3*v3.y);
        acc.z += fmaf(e0, v0.z, e1*v1.z) + fmaf(e2, v2.z, e3*v3.z);
        acc.w += fmaf(e0, v0.w, e1*v1.w) + fmaf(e2, v2.w, e3*v3.w);
    }

    // append the new token (GQA: head h uses kv-head h/4) on the last split
    if (split == NSPLIT - 1 && sub == 0) {
        const float4 kn = ((const float4*)(ws + OFF_KROPE + (size_t)(b*NKV + (h>>2)) * HD))[l32];
        const float4 vn = ((const float4*)(ws + OFF_VRAW  + (size_t)(b*NKV + (h>>2)) * HD))[l32];
        float sv = dot4(q4, kn);
        #pragma unroll
        for (int off = 16; off; off >>= 1) sv += __shfl_xor(sv, off, 64);
        sv *= SCALE;
        const float newm = fmaxf(m, sv);
        const float r_ = __expf(m - newm);
        const float e  = __expf(sv - newm);
        m = newm;
        l = fmaf(l, r_, e);
        acc.x = fmaf(acc.x, r_, e*vn.x);
        acc.y = fmaf(acc.y, r_, e*vn.y);
        acc.z = fmaf(acc.z, r_, e*vn.z);
        acc.w = fmaf(acc.w, r_, e*vn.w);
    }

    // merge the two half-wave states (m may differ only via the new-token path)
    const float M  = fmaxf(m, __shfl_xor(m, 32, 64));
    const float r2_ = __expf(m - M);
    l *= r2_; acc.x *= r2_; acc.y *= r2_; acc.z *= r2_; acc.w *= r2_;
    l     += __shfl_xor(l,     32, 64);
    acc.x += __shfl_xor(acc.x, 32, 64);
    acc.y += __shfl_xor(acc.y, 32, 64);
    acc.z += __shfl_xor(acc.z, 32, 64);
    acc.w += __shfl_xor(acc.w, 32, 64);

    if (sub == 0) {
        float* pp = ws + OFF_PART + ((size_t)pair * NSPLIT + split) * PART_STRIDE;
        ((float4*)pp)[l32] = acc;
        if (l32 == 0) { pp[HD] = M; pp[HD+1] = l; }
    }
}

// ---------------- K3: combine splits (block per (b,h))
__global__ __launch_bounds__(128) void k_combine(float* __restrict__ ws)
{
    const int pair = blockIdx.x;
    const int d = threadIdx.x;
    const float* pp = ws + OFF_PART + (size_t)pair * NSPLIT * PART_STRIDE;
    __shared__ float sm[NSPLIT], sl[NSPLIT];
    if (d < NSPLIT) { sm[d] = pp[d*PART_STRIDE + HD]; sl[d] = pp[d*PART_STRIDE + HD + 1]; }
    __syncthreads();
    float M = -1e30f;
    #pragma unroll
    for (int s = 0; s < NSPLIT; ++s) M = fmaxf(M, sm[s]);
    float L = 0.f, acc = 0.f;
    #pragma unroll 8
    for (int s = 0; s < NSPLIT; ++s) {
        const float w = expf(sm[s] - M);
        L += sl[s] * w;
        acc = fmaf(pp[s*PART_STRIDE + d], w, acc);
    }
    ws[OFF_CTX + (size_t)pair*HD + d] = acc / L;
}

// ---------------- K4: output projection (wave per row, 8-batch accum)
__global__ __launch_bounds__(256) void k_oproj(
    const float* __restrict__ Wo, const float* __restrict__ ws, float* __restrict__ out)
{
    const int wid  = threadIdx.x >> 6;
    const int lane = threadIdx.x & 63;
    const int row  = blockIdx.x * 4 + wid;   // 0..4095
    const float4* Wr = (const float4*)(Wo + (size_t)row * DD);
    const float4* C  = (const float4*)(ws + OFF_CTX);
    float acc[BB];
    #pragma unroll
    for (int b = 0; b < BB; ++b) acc[b] = 0.f;
    for (int it = 0; it < DD/256; ++it) {
        const int idx = it*64 + lane;
        const float4 w4 = ntload4(&Wr[idx]);
        #pragma unroll
        for (int b = 0; b < BB; ++b) {
            const float4 h4 = C[b*(DD/4) + idx];
            acc[b] = fmaf(w4.x, h4.x, fmaf(w4.y, h4.y, fmaf(w4.z, h4.z, fmaf(w4.w, h4.w, acc[b]))));
        }
    }
    #pragma unroll
    for (int b = 0; b < BB; ++b) {
        float v = acc[b];
        #pragma unroll
        for (int off = 32; off; off >>= 1) v += __shfl_xor(v, off, 64);
        if (lane == 0) out[(size_t)b*DD + row] = v;
    }
}

extern "C" void kernel_launch(void* const* d_in, const int* in_sizes, int n_in,
                              void* d_out, int out_size, void* d_ws, size_t ws_size,
                              hipStream_t stream)
{
    const float* hs  = (const float*)d_in[0];
    const float* pk  = (const float*)d_in[1];
    const float* pv  = (const float*)d_in[2];
    const float* Wq  = (const float*)d_in[3];
    const float* bq  = (const float*)d_in[4];
    const float* Wk  = (const float*)d_in[5];
    const float* bk  = (const float*)d_in[6];
    const float* Wv  = (const float*)d_in[7];
    const float* bv  = (const float*)d_in[8];
    const float* Wo  = (const float*)d_in[9];
    const int*   pos = (const int*)d_in[10];
    float* out = (float*)d_out;
    float* ws  = (float*)d_ws;

    k_qkv    <<<3072/4,          256, 0, stream>>>(hs, Wq, bq, Wk, bk, Wv, bv, pos, ws);
    k_attn   <<<BB*NHQ*NSPLIT/4, 256, 0, stream>>>(pk, pv, ws);
    k_combine<<<BB*NHQ,          128, 0, stream>>>(ws);
    k_oproj  <<<4096/4,          256, 0, stream>>>(Wo, ws, out);
}